// Round 4
// baseline (256.636 us; speedup 1.0000x reference)
//
#include <hip/hip_runtime.h>
#include <stdint.h>

#define B_      32
#define T_IN_   512
#define N_      543
#define C_      3
#define NEW_T_  426     // int(512/1.2)
#define JF_     53      // max(1, 426//8)
#define NC_     (N_*C_)             // 1629
#define XOUT_   (B_*NEW_T_*NC_)     // 22206528
#define NFR_    (B_*NEW_T_)         // 13632 frames
#define GPF_    408                 // groups per frame: ceil(1629/4)
#define FPB_    6                   // frames per block strip
#define NTB_    71                  // 426 / 6, exact
#define NBLKM_  (NTB_*B_)           // 2272 = 8 * 284 exactly
#define CPX_    284                 // blocks per XCD chunk (bijective: 2272 % 8 == 0)

#define MODE_INT   0
#define MODE_BYTE  1
#define MODE_FLOAT 2

// 16-byte vector, 4-byte alignment (frame stride 1629 floats is odd).
typedef float f4u __attribute__((vector_size(16), aligned(4)));

__device__ __forceinline__ bool read_flag(const void* p, int mode, int idx) {
    if (mode == MODE_BYTE)  return ((const uint8_t*)p)[idx] != 0;
    if (mode == MODE_FLOAT) return ((const float*)p)[idx]   != 0.0f;
    return ((const int*)p)[idx] != 0;
}

// One block per batch. Builds per-(b,t): 4 frame indices + 4 weights for pd[b,t],
// jitter value (0 at t=0), and writes the mask output.
// Kept frames get F=(i0,i0+1,i0,i0+1), W=(1-w,w,0,0): main skips the zero-weight
// taps via a wave-uniform branch (all lanes of a main wave share the frame).
__global__ __launch_bounds__(512) void prep_kernel(
    const void* __restrict__ maskp,
    const void* __restrict__ keepp,
    const float* __restrict__ bjit,
    float* __restrict__ out_mask,
    int4*  __restrict__ wsF,
    float4* __restrict__ wsW,
    float* __restrict__ wsJ)
{
    const int b = blockIdx.x;
    const int tid = threadIdx.x;

    __shared__ int flags[6];
    __shared__ int s_mode_mask, s_mode_keep;
    if (tid < 6) flags[tid] = 0;
    __syncthreads();
    if (tid < 64) {
        uint32_t vm = ((const uint32_t*)maskp)[tid];
        uint32_t vk = ((const uint32_t*)keepp)[tid];
        if (vm == 0x3F800000u)      atomicOr(&flags[2], 1);
        else if (vm > 1u)           atomicOr(&flags[1], 1);
        if (vk == 0x3F800000u)      atomicOr(&flags[5], 1);
        else if (vk > 1u)           atomicOr(&flags[4], 1);
    }
    __syncthreads();
    if (tid == 0) {
        s_mode_mask = flags[2] ? MODE_FLOAT : (flags[1] ? MODE_BYTE : MODE_INT);
        s_mode_keep = flags[5] ? MODE_FLOAT : (flags[4] ? MODE_BYTE : MODE_INT);
    }
    __syncthreads();
    const int mmode = s_mode_mask, kmode = s_mode_keep;

    __shared__ int sk[512];
    __shared__ int ps[512];
    __shared__ int kept[NEW_T_];

    int kv = 0;
    if (tid < NEW_T_) kv = read_flag(keepp, kmode, b*NEW_T_ + tid) ? 1 : 0;
    sk[tid] = (tid < NEW_T_) ? kv : 0;
    ps[tid] = sk[tid];
    __syncthreads();
    for (int off = 1; off < 512; off <<= 1) {
        int v = (tid >= off) ? ps[tid - off] : 0;
        __syncthreads();
        ps[tid] += v;
        __syncthreads();
    }
    const int K = ps[NEW_T_ - 1];
    if (tid < NEW_T_ && kv) kept[ps[tid] - 1] = tid;
    __syncthreads();

    if (tid < NEW_T_) {
        const int t = tid;
        const float RATX = (float)(511.0 / 425.0);
        float st = (float)t * RATX;
        int i0 = (int)floorf(st);
        if (i0 < 0) i0 = 0; if (i0 > T_IN_ - 2) i0 = T_IN_ - 2;
        float w = st - (float)i0;

        int4 F; float4 W;
        if (kv) {
            F = make_int4(i0, i0 + 1, i0, i0 + 1);
            W = make_float4(1.0f - w, w, 0.0f, 0.0f);
        } else {
            float s = ((float)t * (float)(K - 1)) / 425.0f;
            int r0 = (int)floorf(s);
            if (r0 < 0) r0 = 0; if (r0 > K - 2) r0 = K - 2;
            float f = s - (float)r0;
            int j0 = kept[r0], j1 = kept[r0 + 1];
            float s0 = (float)j0 * RATX;
            int a0 = (int)floorf(s0);
            if (a0 < 0) a0 = 0; if (a0 > T_IN_ - 2) a0 = T_IN_ - 2;
            float w0 = s0 - (float)a0;
            float s1 = (float)j1 * RATX;
            int a1 = (int)floorf(s1);
            if (a1 < 0) a1 = 0; if (a1 > T_IN_ - 2) a1 = T_IN_ - 2;
            float w1 = s1 - (float)a1;
            F = make_int4(a0, a0 + 1, a1, a1 + 1);
            W = make_float4((1.0f - f) * (1.0f - w0), (1.0f - f) * w0,
                            f * (1.0f - w1),          f * w1);
        }
        const int bt = b * NEW_T_ + t;
        wsF[bt] = F;
        wsW[bt] = W;

        const float RATJ = (float)(52.0 / 425.0);
        float sj = (float)t * RATJ;
        int ji = (int)floorf(sj);
        if (ji < 0) ji = 0; if (ji > JF_ - 2) ji = JF_ - 2;
        float jf = sj - (float)ji;
        float b0 = bjit[b*JF_ + ji]     * 0.02f;
        float b1 = bjit[b*JF_ + ji + 1] * 0.02f;
        float jv = b0 * (1.0f - jf) + b1 * jf;
        if (t == 0) jv = 0.0f;
        wsJ[bt] = jv;

        float mn = (float)t * (float)(512.0 / 426.0);
        int nidx = (int)floorf(mn);
        if (nidx > T_IN_ - 1) nidx = T_IN_ - 1;
        bool mo = read_flag(maskp, mmode, b*T_IN_ + nidx) && (kv != 0);
        out_mask[bt] = mo ? 1.0f : 0.0f;
    }
}

// One block per (batch b, strip of FPB_=6 consecutive frames), XCD-swizzled.
// R3 falsified the demand-BW theory (FETCH -17%, time flat). Diagnosis: the
// compiler re-serialized R2's phase split (VGPR=48 < the 60 needed for 15 loads
// in flight) -> avg outstanding ~4.5 KB/CU vs the ~10.5 KB needed to saturate.
// NEW this round: chunked issue-ahead pipeline PINNED with sched_barrier(0) so
// the scheduler cannot collapse it. Strip = 3 chunks x 2 frames; issue regions:
//  [prologue + chunk0 loads] | [chunk1 loads] | [compute c0] | [chunk2 loads] |
//  [compute c1] | [compute c2]
// Each issue group is its own scheduling region, so vmcnt counting keeps chunk
// k+1's 6 loads outstanding across chunk k's compute by construction. Rare
// (~10%) dropped-frame v2/v3 taps still load late inside compute (wave-uniform).
__global__ __launch_bounds__(448) __attribute__((amdgpu_waves_per_eu(4, 8)))
void main_kernel(
    const float* __restrict__ x,
    const float* __restrict__ noise,
    const float* __restrict__ spat,
    const int4*  __restrict__ wsF,
    const float4* __restrict__ wsW,
    const float* __restrict__ wsJ,
    float* __restrict__ out)
{
    const int j = threadIdx.x;
    if (j >= GPF_) return;                       // no barriers below; safe
    // XCD-aware bijective swizzle (nwg % 8 == 0): each XCD gets 4 whole batches
    const uint32_t bid = blockIdx.x;
    const uint32_t swz = (bid & 7u) * CPX_ + (bid >> 3);
    const int b  = (int)(swz / (uint32_t)NTB_);
    const int t0 = (int)(swz % (uint32_t)NTB_) * FPB_;

    uint32_t e0 = (uint32_t)j * 4u;
    if (e0 > (uint32_t)(NC_ - 4)) e0 = (uint32_t)(NC_ - 4);   // tail overlap writes identical values

    const float* __restrict__ xb = x + (size_t)b * (T_IN_ * NC_);
    const int bt0 = b * NEW_T_ + t0;

    // ---- Phase A: block-uniform ws loads (scalar s_loads) ----
    int4   F[FPB_]; float4 W[FPB_]; float jv[FPB_];
    #pragma unroll
    for (int i = 0; i < FPB_; ++i) {
        F[i]  = wsF[bt0 + i];
        W[i]  = wsW[bt0 + i];
        jv[i] = wsJ[bt0 + i];
    }
    const int pbt = b * NEW_T_ + (t0 ? t0 - 1 : 0);
    const int4   Fp = wsF[pbt];
    const float4 Wp = wsW[pbt];
    __builtin_amdgcn_sched_barrier(0);

    // ---- Issue region 0: prologue taps + sp + chunk0 (frames 0,1) ----
    f4u v0[FPB_], v1[FPB_], nz[FPB_];            // constant-indexed only (rule #20)
    f4u q0 = *(const f4u*)(xb + (uint32_t)Fp.x * NC_ + e0);
    f4u q1 = *(const f4u*)(xb + (uint32_t)Fp.y * NC_ + e0);
    const f4u sp = *(const f4u*)(spat + (size_t)b * NC_ + e0);
    #pragma unroll
    for (int i = 0; i < 2; ++i) {
        v0[i] = *(const f4u*)(xb + (uint32_t)F[i].x * NC_ + e0);
        v1[i] = *(const f4u*)(xb + (uint32_t)F[i].y * NC_ + e0);
        nz[i] = __builtin_nontemporal_load((const f4u*)(noise + (size_t)(bt0 + i) * NC_ + e0));
    }
    __builtin_amdgcn_sched_barrier(0);

    // ---- Issue region 1: chunk1 (frames 2,3) — stays outstanding over compute c0 ----
    #pragma unroll
    for (int i = 2; i < 4; ++i) {
        v0[i] = *(const f4u*)(xb + (uint32_t)F[i].x * NC_ + e0);
        v1[i] = *(const f4u*)(xb + (uint32_t)F[i].y * NC_ + e0);
        nz[i] = __builtin_nontemporal_load((const f4u*)(noise + (size_t)(bt0 + i) * NC_ + e0));
    }
    __builtin_amdgcn_sched_barrier(0);

    // ---- Compute region 0: ap + frames 0,1 ----
    f4u ap = Wp.x * q0 + Wp.y * q1;
    if (Wp.z != 0.0f || Wp.w != 0.0f) {          // wave-uniform (scalar W)
        f4u q2 = *(const f4u*)(xb + (uint32_t)Fp.z * NC_ + e0);
        f4u q3 = *(const f4u*)(xb + (uint32_t)Fp.w * NC_ + e0);
        ap += Wp.z * q2 + Wp.w * q3;
    }
    #pragma unroll
    for (int i = 0; i < 2; ++i) {
        f4u a = W[i].x * v0[i] + W[i].y * v1[i];
        if (W[i].z != 0.0f || W[i].w != 0.0f) {  // wave-uniform: dropped frames only (~10%)
            f4u v2 = *(const f4u*)(xb + (uint32_t)F[i].z * NC_ + e0);
            f4u v3 = *(const f4u*)(xb + (uint32_t)F[i].w * NC_ + e0);
            a += W[i].z * v2 + W[i].w * v3;      // skipped terms are exactly 0*x
        }
        f4u r = a + (a - ap) * jv[i] + nz[i] * 0.01f + sp * 0.005f;
        __builtin_nontemporal_store(r, (f4u*)(out + (size_t)(bt0 + i) * NC_ + e0));
        ap = a;
    }
    __builtin_amdgcn_sched_barrier(0);

    // ---- Issue region 2: chunk2 (frames 4,5) — stays outstanding over compute c1 ----
    #pragma unroll
    for (int i = 4; i < 6; ++i) {
        v0[i] = *(const f4u*)(xb + (uint32_t)F[i].x * NC_ + e0);
        v1[i] = *(const f4u*)(xb + (uint32_t)F[i].y * NC_ + e0);
        nz[i] = __builtin_nontemporal_load((const f4u*)(noise + (size_t)(bt0 + i) * NC_ + e0));
    }
    __builtin_amdgcn_sched_barrier(0);

    // ---- Compute region 1: frames 2,3 ----
    #pragma unroll
    for (int i = 2; i < 4; ++i) {
        f4u a = W[i].x * v0[i] + W[i].y * v1[i];
        if (W[i].z != 0.0f || W[i].w != 0.0f) {
            f4u v2 = *(const f4u*)(xb + (uint32_t)F[i].z * NC_ + e0);
            f4u v3 = *(const f4u*)(xb + (uint32_t)F[i].w * NC_ + e0);
            a += W[i].z * v2 + W[i].w * v3;
        }
        f4u r = a + (a - ap) * jv[i] + nz[i] * 0.01f + sp * 0.005f;
        __builtin_nontemporal_store(r, (f4u*)(out + (size_t)(bt0 + i) * NC_ + e0));
        ap = a;
    }
    __builtin_amdgcn_sched_barrier(0);

    // ---- Compute region 2: frames 4,5 ----
    #pragma unroll
    for (int i = 4; i < 6; ++i) {
        f4u a = W[i].x * v0[i] + W[i].y * v1[i];
        if (W[i].z != 0.0f || W[i].w != 0.0f) {
            f4u v2 = *(const f4u*)(xb + (uint32_t)F[i].z * NC_ + e0);
            f4u v3 = *(const f4u*)(xb + (uint32_t)F[i].w * NC_ + e0);
            a += W[i].z * v2 + W[i].w * v3;
        }
        f4u r = a + (a - ap) * jv[i] + nz[i] * 0.01f + sp * 0.005f;
        __builtin_nontemporal_store(r, (f4u*)(out + (size_t)(bt0 + i) * NC_ + e0));
        ap = a;
    }
}

extern "C" void kernel_launch(void* const* d_in, const int* in_sizes, int n_in,
                              void* d_out, int out_size, void* d_ws, size_t ws_size,
                              hipStream_t stream) {
    const float* x    = (const float*)d_in[0];
    const void*  mask = d_in[1];
    const void*  keep = d_in[2];
    const float* bjit = (const float*)d_in[3];
    const float* noise = (const float*)d_in[4];
    const float* spat  = (const float*)d_in[5];
    float* out = (float*)d_out;

    char* ws = (char*)d_ws;
    int4*   wsF = (int4*)ws;                           // 218112 B
    float4* wsW = (float4*)(ws + 218112);              // 218112 B
    float*  wsJ = (float*)(ws + 436224);               // 54528 B

    prep_kernel<<<B_, 512, 0, stream>>>(mask, keep, bjit,
                                        out + XOUT_, wsF, wsW, wsJ);
    main_kernel<<<NBLKM_, 448, 0, stream>>>(x, noise, spat, wsF, wsW, wsJ, out);
}

// Round 5
// 252.929 us; speedup vs baseline: 1.0147x; 1.0147x over previous
//
#include <hip/hip_runtime.h>
#include <stdint.h>

#define B_      32
#define T_IN_   512
#define N_      543
#define C_      3
#define NEW_T_  426     // int(512/1.2)
#define JF_     53      // max(1, 426//8)
#define NC_     (N_*C_)             // 1629
#define XOUT_   (B_*NEW_T_*NC_)     // 22206528
#define NFR_    (B_*NEW_T_)         // 13632 frames
#define GPF_    408                 // groups per frame: ceil(1629/4)
#define FPB_    6                   // frames per block strip
#define NTB_    71                  // 426 / 6, exact
#define NBLKM_  (NTB_*B_)           // 2272 = 8 * 284 exactly
#define CPX_    284                 // blocks per XCD chunk (bijective: 2272 % 8 == 0)

#define MODE_INT   0
#define MODE_BYTE  1
#define MODE_FLOAT 2

// 16-byte vector, 4-byte alignment (frame stride 1629 floats is odd).
typedef float f4u __attribute__((vector_size(16), aligned(4)));

__device__ __forceinline__ bool read_flag(const void* p, int mode, int idx) {
    if (mode == MODE_BYTE)  return ((const uint8_t*)p)[idx] != 0;
    if (mode == MODE_FLOAT) return ((const float*)p)[idx]   != 0.0f;
    return ((const int*)p)[idx] != 0;
}

// One block per batch. Builds per-(b,t): 4 frame indices + 4 weights for pd[b,t],
// jitter value (0 at t=0), and writes the mask output.
// Kept frames get F=(i0,i0+1,i0,i0+1), W=(1-w,w,0,0): main skips the zero-weight
// taps via a wave-uniform branch (all lanes of a main wave share the frame).
__global__ __launch_bounds__(512) void prep_kernel(
    const void* __restrict__ maskp,
    const void* __restrict__ keepp,
    const float* __restrict__ bjit,
    float* __restrict__ out_mask,
    int4*  __restrict__ wsF,
    float4* __restrict__ wsW,
    float* __restrict__ wsJ)
{
    const int b = blockIdx.x;
    const int tid = threadIdx.x;

    __shared__ int flags[6];
    __shared__ int s_mode_mask, s_mode_keep;
    if (tid < 6) flags[tid] = 0;
    __syncthreads();
    if (tid < 64) {
        uint32_t vm = ((const uint32_t*)maskp)[tid];
        uint32_t vk = ((const uint32_t*)keepp)[tid];
        if (vm == 0x3F800000u)      atomicOr(&flags[2], 1);
        else if (vm > 1u)           atomicOr(&flags[1], 1);
        if (vk == 0x3F800000u)      atomicOr(&flags[5], 1);
        else if (vk > 1u)           atomicOr(&flags[4], 1);
    }
    __syncthreads();
    if (tid == 0) {
        s_mode_mask = flags[2] ? MODE_FLOAT : (flags[1] ? MODE_BYTE : MODE_INT);
        s_mode_keep = flags[5] ? MODE_FLOAT : (flags[4] ? MODE_BYTE : MODE_INT);
    }
    __syncthreads();
    const int mmode = s_mode_mask, kmode = s_mode_keep;

    __shared__ int sk[512];
    __shared__ int ps[512];
    __shared__ int kept[NEW_T_];

    int kv = 0;
    if (tid < NEW_T_) kv = read_flag(keepp, kmode, b*NEW_T_ + tid) ? 1 : 0;
    sk[tid] = (tid < NEW_T_) ? kv : 0;
    ps[tid] = sk[tid];
    __syncthreads();
    for (int off = 1; off < 512; off <<= 1) {
        int v = (tid >= off) ? ps[tid - off] : 0;
        __syncthreads();
        ps[tid] += v;
        __syncthreads();
    }
    const int K = ps[NEW_T_ - 1];
    if (tid < NEW_T_ && kv) kept[ps[tid] - 1] = tid;
    __syncthreads();

    if (tid < NEW_T_) {
        const int t = tid;
        const float RATX = (float)(511.0 / 425.0);
        float st = (float)t * RATX;
        int i0 = (int)floorf(st);
        if (i0 < 0) i0 = 0; if (i0 > T_IN_ - 2) i0 = T_IN_ - 2;
        float w = st - (float)i0;

        int4 F; float4 W;
        if (kv) {
            F = make_int4(i0, i0 + 1, i0, i0 + 1);
            W = make_float4(1.0f - w, w, 0.0f, 0.0f);
        } else {
            float s = ((float)t * (float)(K - 1)) / 425.0f;
            int r0 = (int)floorf(s);
            if (r0 < 0) r0 = 0; if (r0 > K - 2) r0 = K - 2;
            float f = s - (float)r0;
            int j0 = kept[r0], j1 = kept[r0 + 1];
            float s0 = (float)j0 * RATX;
            int a0 = (int)floorf(s0);
            if (a0 < 0) a0 = 0; if (a0 > T_IN_ - 2) a0 = T_IN_ - 2;
            float w0 = s0 - (float)a0;
            float s1 = (float)j1 * RATX;
            int a1 = (int)floorf(s1);
            if (a1 < 0) a1 = 0; if (a1 > T_IN_ - 2) a1 = T_IN_ - 2;
            float w1 = s1 - (float)a1;
            F = make_int4(a0, a0 + 1, a1, a1 + 1);
            W = make_float4((1.0f - f) * (1.0f - w0), (1.0f - f) * w0,
                            f * (1.0f - w1),          f * w1);
        }
        const int bt = b * NEW_T_ + t;
        wsF[bt] = F;
        wsW[bt] = W;

        const float RATJ = (float)(52.0 / 425.0);
        float sj = (float)t * RATJ;
        int ji = (int)floorf(sj);
        if (ji < 0) ji = 0; if (ji > JF_ - 2) ji = JF_ - 2;
        float jf = sj - (float)ji;
        float b0 = bjit[b*JF_ + ji]     * 0.02f;
        float b1 = bjit[b*JF_ + ji + 1] * 0.02f;
        float jv = b0 * (1.0f - jf) + b1 * jf;
        if (t == 0) jv = 0.0f;
        wsJ[bt] = jv;

        float mn = (float)t * (float)(512.0 / 426.0);
        int nidx = (int)floorf(mn);
        if (nidx > T_IN_ - 1) nidx = T_IN_ - 1;
        bool mo = read_flag(maskp, mmode, b*T_IN_ + nidx) && (kv != 0);
        out_mask[bt] = mo ? 1.0f : 0.0f;
    }
}

// One block per (batch b, strip of FPB_=6 consecutive frames), XCD-swizzled.
// R3/R4 falsified demand-BW, locality, and concurrency theories (FETCH -17% flat,
// forced pipeline flat). Remaining invariant across all rounds: WRITE_SIZE ~90 MB
// at a constant ~1.1 TB/s drain = the 82 us floor. All rounds used NONTEMPORAL
// stores on a 4-mod-16-aligned stream (frame stride 6516 B): nt bypasses L2
// write-combining, misaligned 16B nt lane-stores reach DRAM as partial-line
// bursts -> read-modify-write at HBM -> write BW collapse.
// SINGLE delta this round: stores are regular cached stores (L2 write-combines
// the contiguous wave stores into full 64B lines before writeback). noise keeps
// its nt LOAD (loads don't RMW). sched_barriers of R4 reverted (they cost +5us).
__global__ __launch_bounds__(448) __attribute__((amdgpu_waves_per_eu(4, 8)))
void main_kernel(
    const float* __restrict__ x,
    const float* __restrict__ noise,
    const float* __restrict__ spat,
    const int4*  __restrict__ wsF,
    const float4* __restrict__ wsW,
    const float* __restrict__ wsJ,
    float* __restrict__ out)
{
    const int j = threadIdx.x;
    if (j >= GPF_) return;                       // no barriers below; safe
    // XCD-aware bijective swizzle (nwg % 8 == 0): each XCD gets 4 whole batches
    const uint32_t bid = blockIdx.x;
    const uint32_t swz = (bid & 7u) * CPX_ + (bid >> 3);
    const int b  = (int)(swz / (uint32_t)NTB_);
    const int t0 = (int)(swz % (uint32_t)NTB_) * FPB_;

    uint32_t e0 = (uint32_t)j * 4u;
    if (e0 > (uint32_t)(NC_ - 4)) e0 = (uint32_t)(NC_ - 4);   // tail overlap writes identical values

    const float* __restrict__ xb = x + (size_t)b * (T_IN_ * NC_);
    const int bt0 = b * NEW_T_ + t0;

    // ---- Phase A: block-uniform ws loads (scalar s_loads) ----
    int4   F[FPB_]; float4 W[FPB_]; float jv[FPB_];
    #pragma unroll
    for (int i = 0; i < FPB_; ++i) {
        F[i]  = wsF[bt0 + i];
        W[i]  = wsW[bt0 + i];
        jv[i] = wsJ[bt0 + i];
    }
    const int pbt = b * NEW_T_ + (t0 ? t0 - 1 : 0);
    const int4   Fp = wsF[pbt];
    const float4 Wp = wsW[pbt];

    // ---- Phase B: issue every primary load back-to-back (nothing consumed yet) ----
    f4u v0[FPB_], v1[FPB_], nz[FPB_];
    #pragma unroll
    for (int i = 0; i < FPB_; ++i) {
        v0[i] = *(const f4u*)(xb + (uint32_t)F[i].x * NC_ + e0);
        v1[i] = *(const f4u*)(xb + (uint32_t)F[i].y * NC_ + e0);
    }
    f4u q0 = *(const f4u*)(xb + (uint32_t)Fp.x * NC_ + e0);
    f4u q1 = *(const f4u*)(xb + (uint32_t)Fp.y * NC_ + e0);
    #pragma unroll
    for (int i = 0; i < FPB_; ++i)
        nz[i] = __builtin_nontemporal_load((const f4u*)(noise + (size_t)(bt0 + i) * NC_ + e0));
    const f4u sp = *(const f4u*)(spat + (size_t)b * NC_ + e0);

    // ---- prologue combine: ap = interp of frame t0-1 (t=0 has jitter 0) ----
    f4u ap = Wp.x * q0 + Wp.y * q1;
    if (Wp.z != 0.0f || Wp.w != 0.0f) {          // wave-uniform (scalar W)
        f4u q2 = *(const f4u*)(xb + (uint32_t)Fp.z * NC_ + e0);
        f4u q3 = *(const f4u*)(xb + (uint32_t)Fp.w * NC_ + e0);
        ap += Wp.z * q2 + Wp.w * q3;
    }

    // ---- Phase C: combine in order, carrying ap ----
    #pragma unroll
    for (int i = 0; i < FPB_; ++i) {
        f4u a = W[i].x * v0[i] + W[i].y * v1[i];
        if (W[i].z != 0.0f || W[i].w != 0.0f) {  // wave-uniform: dropped frames only (~10%)
            f4u v2 = *(const f4u*)(xb + (uint32_t)F[i].z * NC_ + e0);
            f4u v3 = *(const f4u*)(xb + (uint32_t)F[i].w * NC_ + e0);
            a += W[i].z * v2 + W[i].w * v3;      // skipped terms are exactly 0*x
        }
        f4u r = a + (a - ap) * jv[i] + nz[i] * 0.01f + sp * 0.005f;
        *(f4u*)(out + (size_t)(bt0 + i) * NC_ + e0) = r;   // REGULAR store: L2 write-combine
        ap = a;                                   // register-carried: replaces 4 Q-loads
    }
}

extern "C" void kernel_launch(void* const* d_in, const int* in_sizes, int n_in,
                              void* d_out, int out_size, void* d_ws, size_t ws_size,
                              hipStream_t stream) {
    const float* x    = (const float*)d_in[0];
    const void*  mask = d_in[1];
    const void*  keep = d_in[2];
    const float* bjit = (const float*)d_in[3];
    const float* noise = (const float*)d_in[4];
    const float* spat  = (const float*)d_in[5];
    float* out = (float*)d_out;

    char* ws = (char*)d_ws;
    int4*   wsF = (int4*)ws;                           // 218112 B
    float4* wsW = (float4*)(ws + 218112);              // 218112 B
    float*  wsJ = (float*)(ws + 436224);               // 54528 B

    prep_kernel<<<B_, 512, 0, stream>>>(mask, keep, bjit,
                                        out + XOUT_, wsF, wsW, wsJ);
    main_kernel<<<NBLKM_, 448, 0, stream>>>(x, noise, spat, wsF, wsW, wsJ, out);
}